// Round 8
// baseline (1613.992 us; speedup 1.0000x reference)
//
#include <hip/hip_runtime.h>
#include <hip/hip_bf16.h>

#define C 64  // channels

// bf16 <-> f32 helpers (bit-level, RNE on pack)
__device__ __forceinline__ float b2f(unsigned short s) {
    return __uint_as_float(((unsigned int)s) << 16);
}
__device__ __forceinline__ unsigned short f2b(float f) {
    unsigned int u = __float_as_uint(f);
    u = (u + 0x7FFF + ((u >> 16) & 1)) >> 16;
    return (unsigned short)u;
}

// ---------------------------------------------------------------------------
// Fused MLP: h = relu(relu(x @ W1) @ W2).  PROVEN R4 form, byte-identical
// (163us, VGPR 64, WRITE 37.5MB).  DO NOT restructure: R1 reg-prefetch
// spilled (WRITE 190MB); R6 k-chunked GEMM2 spilled (VGPR 256, 360us).
// ---------------------------------------------------------------------------
__launch_bounds__(256)
__global__ void mlp_kernel(const float* __restrict__ x,
                           const float* __restrict__ W1,
                           const float* __restrict__ W2,
                           float* __restrict__ h0,
                           unsigned short* __restrict__ hb, int nN)
{
    __shared__ float smem[8704];
    float (*As)[68] = (float(*)[68])smem;            // 64 x 68
    float (*Bs)[68] = (float(*)[68])(smem + 4352);   // 64 x 68
    float (*Hs)[68] = (float(*)[68])smem;            // GEMM2 reuse
    float (*Ws)[68] = (float(*)[68])(smem + 4352);

    const int t  = threadIdx.x;
    const int ty = t >> 4;
    const int tx = t & 15;
    const int row0 = blockIdx.x * 64;

    const int srow = t >> 4;
    const int slk  = (t & 15) * 4;

    float acc[4][4] = {};

    for (int k0 = 0; k0 < 512; k0 += 64) {
        #pragma unroll
        for (int h = 0; h < 4; ++h) {
            int r = srow + 16 * h;
            int grow = row0 + r;
            float4 v = make_float4(0.f, 0.f, 0.f, 0.f);
            if (grow < nN) v = *(const float4*)&x[(size_t)grow * 512 + k0 + slk];
            *(float4*)&As[r][slk] = v;
        }
        #pragma unroll
        for (int h = 0; h < 4; ++h) {
            int r = srow + 16 * h;
            *(float4*)&Bs[r][slk] = *(const float4*)&W1[(size_t)(k0 + r) * 64 + slk];
        }
        __syncthreads();

        for (int kk = 0; kk < 64; kk += 4) {
            float4 b0 = *(float4*)&Bs[kk + 0][tx * 4];
            float4 b1 = *(float4*)&Bs[kk + 1][tx * 4];
            float4 b2 = *(float4*)&Bs[kk + 2][tx * 4];
            float4 b3 = *(float4*)&Bs[kk + 3][tx * 4];
            #pragma unroll
            for (int i = 0; i < 4; ++i) {
                float4 a = *(float4*)&As[ty * 4 + i][kk];
                acc[i][0] += a.x * b0.x + a.y * b1.x + a.z * b2.x + a.w * b3.x;
                acc[i][1] += a.x * b0.y + a.y * b1.y + a.z * b2.y + a.w * b3.y;
                acc[i][2] += a.x * b0.z + a.y * b1.z + a.z * b2.z + a.w * b3.z;
                acc[i][3] += a.x * b0.w + a.y * b1.w + a.z * b2.w + a.w * b3.w;
            }
        }
        __syncthreads();
    }

    #pragma unroll
    for (int i = 0; i < 4; ++i) {
        float4 o;
        o.x = acc[i][0] > 0.f ? acc[i][0] : 0.f;
        o.y = acc[i][1] > 0.f ? acc[i][1] : 0.f;
        o.z = acc[i][2] > 0.f ? acc[i][2] : 0.f;
        o.w = acc[i][3] > 0.f ? acc[i][3] : 0.f;
        *(float4*)&Hs[ty * 4 + i][tx * 4] = o;
    }
    #pragma unroll
    for (int qq = 0; qq < 4; ++qq) {
        int r = srow + 16 * qq;
        *(float4*)&Ws[r][slk] = *(const float4*)&W2[(size_t)r * 64 + slk];
    }
    __syncthreads();

    float acc2[4][4] = {};
    for (int kk = 0; kk < 64; kk += 4) {
        float4 b0 = *(float4*)&Ws[kk + 0][tx * 4];
        float4 b1 = *(float4*)&Ws[kk + 1][tx * 4];
        float4 b2 = *(float4*)&Ws[kk + 2][tx * 4];
        float4 b3 = *(float4*)&Ws[kk + 3][tx * 4];
        #pragma unroll
        for (int i = 0; i < 4; ++i) {
            float4 a = *(float4*)&Hs[ty * 4 + i][kk];
            acc2[i][0] += a.x * b0.x + a.y * b1.x + a.z * b2.x + a.w * b3.x;
            acc2[i][1] += a.x * b0.y + a.y * b1.y + a.z * b2.y + a.w * b3.y;
            acc2[i][2] += a.x * b0.z + a.y * b1.z + a.z * b2.z + a.w * b3.z;
            acc2[i][3] += a.x * b0.w + a.y * b1.w + a.z * b2.w + a.w * b3.w;
        }
    }

    #pragma unroll
    for (int i = 0; i < 4; ++i) {
        int grow = row0 + ty * 4 + i;
        if (grow < nN) {
            float4 o;
            o.x = acc2[i][0] > 0.f ? acc2[i][0] : 0.f;
            o.y = acc2[i][1] > 0.f ? acc2[i][1] : 0.f;
            o.z = acc2[i][2] > 0.f ? acc2[i][2] : 0.f;
            o.w = acc2[i][3] > 0.f ? acc2[i][3] : 0.f;
            *(float4*)&h0[(size_t)grow * 64 + tx * 4] = o;
            ushort4 ob = make_ushort4(f2b(o.x), f2b(o.y), f2b(o.z), f2b(o.w));
            *(ushort4*)&hb[(size_t)grow * 64 + tx * 4] = ob;
        }
    }
}

// ---------------------------------------------------------------------------
// Segment-CSR build (R8 cache blocking): key = (src/segW)*nN + dst, 4*nN
// rows.  Segment s's edges gather only from cur rows [s*segW,(s+1)*segW)
// = 3.2MB < 4MB per-XCD L2.  count -> hierarchical scan (4nN) -> fill.
// After fill, rowptr4[r] = END offset; start = rowptr4[r-1] (0 for r=0).
// ---------------------------------------------------------------------------
__launch_bounds__(256)
__global__ void count4(const int* __restrict__ src, const int* __restrict__ dst,
                       int* __restrict__ rp4, int nE, int nN, int segW)
{
    int e = blockIdx.x * 256 + threadIdx.x;
    if (e < nE) atomicAdd(&rp4[(src[e] / segW) * nN + dst[e]], 1);
}

// per-block exclusive scan of 1024 elements (256 thr x 4), total -> bsum
__launch_bounds__(256)
__global__ void scanA(int* __restrict__ deg, int* __restrict__ bsum, int L)
{
    __shared__ int ts[256];
    const int t = threadIdx.x;
    const int base = blockIdx.x * 1024 + t * 4;
    int v0 = 0, v1 = 0, v2 = 0, v3 = 0;
    if (base + 3 < L) {
        int4 v = *(const int4*)&deg[base];
        v0 = v.x; v1 = v.y; v2 = v.z; v3 = v.w;
    } else {
        if (base + 0 < L) v0 = deg[base + 0];
        if (base + 1 < L) v1 = deg[base + 1];
        if (base + 2 < L) v2 = deg[base + 2];
        if (base + 3 < L) v3 = deg[base + 3];
    }
    int s = v0 + v1 + v2 + v3;
    ts[t] = s;
    __syncthreads();
    for (int d = 1; d < 256; d <<= 1) {
        int xv = (t >= d) ? ts[t - d] : 0;
        __syncthreads();
        ts[t] += xv;
        __syncthreads();
    }
    if (t == 255) bsum[blockIdx.x] = ts[255];
    int e0 = ts[t] - s;
    int e1 = e0 + v0;
    int e2 = e1 + v1;
    int e3 = e2 + v2;
    if (base + 3 < L) {
        *(int4*)&deg[base] = make_int4(e0, e1, e2, e3);
    } else {
        if (base + 0 < L) deg[base + 0] = e0;
        if (base + 1 < L) deg[base + 1] = e1;
        if (base + 2 < L) deg[base + 2] = e2;
        if (base + 3 < L) deg[base + 3] = e3;
    }
}

// exclusive scan of up to 512 block sums, in place (4nN/1024 = 391 for 100k)
__launch_bounds__(512)
__global__ void scanB(int* __restrict__ bsum, int nB)
{
    __shared__ int ts[512];
    const int t = threadIdx.x;
    int v = (t < nB) ? bsum[t] : 0;
    ts[t] = v;
    __syncthreads();
    for (int d = 1; d < 512; d <<= 1) {
        int xv = (t >= d) ? ts[t - d] : 0;
        __syncthreads();
        ts[t] += xv;
        __syncthreads();
    }
    if (t < nB) bsum[t] = ts[t] - v;
}

__launch_bounds__(256)
__global__ void scanC(int* __restrict__ deg, const int* __restrict__ bsum, int L)
{
    const int i4 = (blockIdx.x * 256 + threadIdx.x) * 4;
    if (i4 >= L) return;
    const int b = bsum[i4 >> 10];
    if (i4 + 3 < L) {
        int4 v = *(int4*)&deg[i4];
        v.x += b; v.y += b; v.z += b; v.w += b;
        *(int4*)&deg[i4] = v;
    } else {
        for (int j = 0; j < 4 && i4 + j < L; ++j) deg[i4 + j] += b;
    }
}

__launch_bounds__(256)
__global__ void fill4(const int* __restrict__ src, const int* __restrict__ dst,
                      const float* __restrict__ w,
                      int* __restrict__ rp4,
                      int2* __restrict__ cwp, int nE, int nN, int segW)
{
    int e = blockIdx.x * 256 + threadIdx.x;
    if (e >= nE) return;
    int pos = atomicAdd(&rp4[(src[e] / segW) * nN + dst[e]], 1);
    cwp[pos] = make_int2(src[e], __float_as_int(w[e]));
}

// ---------------------------------------------------------------------------
// Cache-blocked SpMM pass for segment `seg`.  mode 0: acc = partial (init);
// mode 1: acc += partial; mode 2 (last seg): nxt = bf16(acc + partial), and
// idx-tail blocks gate the full fp32 row into out.
// Wave shape: 4 edge slots (g) x 16 channel-quad lanes (q, 8B gather/lane);
// each wave processes V=4 consecutive dst nodes (amortizes per-block
// latency over the multi-batch dispatch).  Gathers in pass s touch only
// cur rows of segment s (3.2MB, L2-resident).
// ---------------------------------------------------------------------------
__launch_bounds__(256)
__global__ void spmm_seg(const int* __restrict__ rowptr4,
                         const int2* __restrict__ cwp,
                         const unsigned short* __restrict__ cur,
                         float* __restrict__ acc,
                         unsigned short* __restrict__ nxt,
                         const int* __restrict__ idx,
                         const float* __restrict__ wp,
                         float* __restrict__ out,
                         int nN, int nI, int seg, int mode, int nodeBlocks)
{
    const int bid  = blockIdx.x;
    const int wid  = threadIdx.x >> 6;
    const int lane = threadIdx.x & 63;
    const int g = lane >> 4;   // edge slot 0..3
    const int q = lane & 15;   // channel quad

    if (bid < nodeBlocks) {
        const int n0 = (bid * 4 + wid) * 4;
        for (int v = 0; v < 4; ++v) {
            const int node = n0 + v;
            if (node >= nN) return;
            const int row = seg * nN + node;
            const int beg = (row == 0) ? 0 : rowptr4[row - 1];
            const int end = rowptr4[row];
            float a0 = 0.f, a1 = 0.f, a2 = 0.f, a3 = 0.f;
            for (int e = beg + g; e < end; e += 4) {
                int2 ce = cwp[e];
                float w = __int_as_float(ce.y);
                ushort4 r = *(const ushort4*)&cur[(size_t)ce.x * 64 + q * 4];
                a0 += w * b2f(r.x); a1 += w * b2f(r.y);
                a2 += w * b2f(r.z); a3 += w * b2f(r.w);
            }
            a0 += __shfl_xor(a0, 16); a0 += __shfl_xor(a0, 32);
            a1 += __shfl_xor(a1, 16); a1 += __shfl_xor(a1, 32);
            a2 += __shfl_xor(a2, 16); a2 += __shfl_xor(a2, 32);
            a3 += __shfl_xor(a3, 16); a3 += __shfl_xor(a3, 32);
            if (g == 0) {
                const size_t off = (size_t)node * 64 + q * 4;
                if (mode == 0) {
                    *(float4*)&acc[off] = make_float4(a0, a1, a2, a3);
                } else {
                    float4 p = *(float4*)&acc[off];
                    p.x += a0; p.y += a1; p.z += a2; p.w += a3;
                    if (mode == 1) {
                        *(float4*)&acc[off] = p;
                    } else {
                        ushort4 ob = make_ushort4(f2b(p.x), f2b(p.y),
                                                  f2b(p.z), f2b(p.w));
                        *(ushort4*)&nxt[off] = ob;
                    }
                }
            }
        }
    } else {
        // idx tail (launched only with mode==2): gate acc + seg partial
        const int oi = (bid - nodeBlocks) * 4 + wid;
        if (oi >= nI) return;
        const int node = idx[oi];
        const int row = seg * nN + node;
        const int beg = (row == 0) ? 0 : rowptr4[row - 1];
        const int end = rowptr4[row];
        float a0 = 0.f, a1 = 0.f, a2 = 0.f, a3 = 0.f;
        for (int e = beg + g; e < end; e += 4) {
            int2 ce = cwp[e];
            float w = __int_as_float(ce.y);
            ushort4 r = *(const ushort4*)&cur[(size_t)ce.x * 64 + q * 4];
            a0 += w * b2f(r.x); a1 += w * b2f(r.y);
            a2 += w * b2f(r.z); a3 += w * b2f(r.w);
        }
        a0 += __shfl_xor(a0, 16); a0 += __shfl_xor(a0, 32);
        a1 += __shfl_xor(a1, 16); a1 += __shfl_xor(a1, 32);
        a2 += __shfl_xor(a2, 16); a2 += __shfl_xor(a2, 32);
        a3 += __shfl_xor(a3, 16); a3 += __shfl_xor(a3, 32);
        float4 p = make_float4(0.f, 0.f, 0.f, 0.f);
        float s = 0.f;
        if (g == 0) {
            p = *(const float4*)&acc[(size_t)node * 64 + q * 4];
            p.x += a0; p.y += a1; p.z += a2; p.w += a3;
            s = p.x * wp[q * 4] + p.y * wp[q * 4 + 1]
              + p.z * wp[q * 4 + 2] + p.w * wp[q * 4 + 3];
        }
        // reduce within the g==0 group (lane bits 0..3)
        s += __shfl_xor(s, 1); s += __shfl_xor(s, 2);
        s += __shfl_xor(s, 4); s += __shfl_xor(s, 8);
        float gate = 1.f / (1.f + __expf(-s));
        if (g == 0) {
            float* op = &out[(size_t)oi * 64 + q * 4];
            float4 pr = *(float4*)op;
            pr.x += gate * p.x; pr.y += gate * p.y;
            pr.z += gate * p.z; pr.w += gate * p.w;
            *(float4*)op = pr;
        }
    }
}

// ---------------------------------------------------------------------------
// Final hop: only idx rows needed.  Walk all 4 segment rows of the node,
// gather from full cur (10k nodes -> misses negligible), gate into out.
// ---------------------------------------------------------------------------
__launch_bounds__(256)
__global__ void spmm_idx(const int* __restrict__ rowptr4,
                         const int2* __restrict__ cwp,
                         const unsigned short* __restrict__ cur,
                         const int* __restrict__ idx,
                         const float* __restrict__ wp,
                         float* __restrict__ out,
                         int nN, int nI)
{
    const int oi = blockIdx.x * 4 + (threadIdx.x >> 6);
    if (oi >= nI) return;
    const int lane = threadIdx.x & 63;
    const int g = lane >> 4;
    const int q = lane & 15;
    const int node = idx[oi];

    float a0 = 0.f, a1 = 0.f, a2 = 0.f, a3 = 0.f;
    for (int s4 = 0; s4 < 4; ++s4) {
        const int row = s4 * nN + node;
        const int beg = (row == 0) ? 0 : rowptr4[row - 1];
        const int end = rowptr4[row];
        for (int e = beg + g; e < end; e += 4) {
            int2 ce = cwp[e];
            float w = __int_as_float(ce.y);
            ushort4 r = *(const ushort4*)&cur[(size_t)ce.x * 64 + q * 4];
            a0 += w * b2f(r.x); a1 += w * b2f(r.y);
            a2 += w * b2f(r.z); a3 += w * b2f(r.w);
        }
    }
    a0 += __shfl_xor(a0, 16); a0 += __shfl_xor(a0, 32);
    a1 += __shfl_xor(a1, 16); a1 += __shfl_xor(a1, 32);
    a2 += __shfl_xor(a2, 16); a2 += __shfl_xor(a2, 32);
    a3 += __shfl_xor(a3, 16); a3 += __shfl_xor(a3, 32);
    float s = 0.f;
    if (g == 0)
        s = a0 * wp[q * 4] + a1 * wp[q * 4 + 1]
          + a2 * wp[q * 4 + 2] + a3 * wp[q * 4 + 3];
    s += __shfl_xor(s, 1); s += __shfl_xor(s, 2);
    s += __shfl_xor(s, 4); s += __shfl_xor(s, 8);
    float gate = 1.f / (1.f + __expf(-s));
    if (g == 0) {
        float* op = &out[(size_t)oi * 64 + q * 4];
        float4 pr = *(float4*)op;
        pr.x += gate * a0; pr.y += gate * a1;
        pr.z += gate * a2; pr.w += gate * a3;
        *(float4*)op = pr;
    }
}

// ---------------------------------------------------------------------------
// Hop-0 gate: out[i] = sigmoid(h[idx[i]].wp) * h[idx[i]]  (fp32 h, inits out)
// ---------------------------------------------------------------------------
__launch_bounds__(256)
__global__ void gate_gather(const float* __restrict__ h,
                            const int* __restrict__ idx,
                            const float* __restrict__ wp,
                            float* __restrict__ out, int nI)
{
    int gid = blockIdx.x * 256 + threadIdx.x;
    int i = gid >> 6;
    if (i >= nI) return;
    int c = gid & 63;
    int n = idx[i];
    float v = h[(size_t)n * 64 + c];
    float s = v * wp[c];
    #pragma unroll
    for (int off = 32; off > 0; off >>= 1)
        s += __shfl_xor(s, off);
    float gate = 1.f / (1.f + __expf(-s));
    out[gid] = gate * v;
}

extern "C" void kernel_launch(void* const* d_in, const int* in_sizes, int n_in,
                              void* d_out, int out_size, void* d_ws, size_t ws_size,
                              hipStream_t stream) {
    const float* x    = (const float*)d_in[0];
    const int*   esrc = (const int*)d_in[1];
    const int*   edst = (const int*)d_in[2];
    const float* ew   = (const float*)d_in[3];
    const int*   nidx = (const int*)d_in[4];
    const float* W1   = (const float*)d_in[5];
    const float* W2   = (const float*)d_in[6];
    const float* wp   = (const float*)d_in[7];
    float* out = (float*)d_out;

    const int nN = in_sizes[0] / 512;
    const int nE = in_sizes[1];
    const int nI = in_sizes[4];

    // ws: h0/acc f32 25.6M | bufA bf16 12.8M | bufB bf16 12.8M |
    //     rowptr4 4*nN int 1.6M | cwp 12.8M        (total ~65.6MB)
    float*          h0     = (float*)d_ws;          // reused as fp32 acc
    unsigned short* bufA   = (unsigned short*)(h0 + (size_t)nN * C);
    unsigned short* bufB   = bufA + (size_t)nN * C;
    int*            rp4    = (int*)(bufB + (size_t)nN * C);
    int2*           cwp    = (int2*)(rp4 + (size_t)4 * nN);
    // scan block sums: bufB head is dead until the first hop writes nxt
    int*            bsum   = (int*)bufB;

    const int segW = (nN + 3) / 4;               // 25000 -> 3.2MB bf16 slice
    const int L    = 4 * nN;
    const int nB   = (L + 1023) / 1024;          // 391 for nN=100k (<=512)

    // --- segment-CSR build ---
    hipMemsetAsync(rp4, 0, (size_t)L * sizeof(int), stream);
    count4<<<(nE + 255) / 256, 256, 0, stream>>>(esrc, edst, rp4, nE, nN, segW);
    scanA<<<nB, 256, 0, stream>>>(rp4, bsum, L);
    scanB<<<1, 512, 0, stream>>>(bsum, nB);
    scanC<<<nB, 256, 0, stream>>>(rp4, bsum, L);
    fill4<<<(nE + 255) / 256, 256, 0, stream>>>(esrc, edst, ew, rp4, cwp, nE, nN, segW);

    // --- MLP (fp32 h0 + bf16 hb) ---
    mlp_kernel<<<(nN + 63) / 64, 256, 0, stream>>>(x, W1, W2, h0, bufA, nN);

    // hop 0 gate (initializes out; h0 is dead afterwards -> becomes acc)
    gate_gather<<<(nI * 64 + 255) / 256, 256, 0, stream>>>(h0, nidx, wp, out, nI);

    unsigned short* cur = bufA;
    unsigned short* nxt = bufB;
    const int nodeBlocks = (nN + 15) / 16;       // V=4 nodes/wave, 4 waves
    const int idxBlocks  = (nI + 3) / 4;
    for (int k = 0; k < 9; ++k) {
        for (int s4 = 0; s4 < 4; ++s4) {
            const int mode = (s4 == 0) ? 0 : ((s4 == 3) ? 2 : 1);
            const int grid = nodeBlocks + ((s4 == 3) ? idxBlocks : 0);
            spmm_seg<<<grid, 256, 0, stream>>>(
                rp4, cwp, cur, h0, nxt, nidx, wp, out, nN, nI, s4, mode, nodeBlocks);
        }
        unsigned short* tmp = cur; cur = nxt; nxt = tmp;
    }
    // final hop: idx rows only, full-table gather
    spmm_idx<<<idxBlocks, 256, 0, stream>>>(rp4, cwp, cur, nidx, wp, out, nN, nI);
}

// Round 9
// 1073.055 us; speedup vs baseline: 1.5041x; 1.5041x over previous
//
#include <hip/hip_runtime.h>
#include <hip/hip_bf16.h>

#define C 64  // channels

// bf16 <-> f32 helpers (bit-level, RNE on pack)
__device__ __forceinline__ float b2f(unsigned short s) {
    return __uint_as_float(((unsigned int)s) << 16);
}
__device__ __forceinline__ unsigned short f2b(float f) {
    unsigned int u = __float_as_uint(f);
    u = (u + 0x7FFF + ((u >> 16) & 1)) >> 16;
    return (unsigned short)u;
}

// accumulate 8 bf16 (int4) * w into a[8]
__device__ __forceinline__ void fma8(float* a, float w, int4 r) {
    a[0] += w * __uint_as_float((unsigned)r.x << 16);
    a[1] += w * __uint_as_float((unsigned)r.x & 0xFFFF0000u);
    a[2] += w * __uint_as_float((unsigned)r.y << 16);
    a[3] += w * __uint_as_float((unsigned)r.y & 0xFFFF0000u);
    a[4] += w * __uint_as_float((unsigned)r.z << 16);
    a[5] += w * __uint_as_float((unsigned)r.z & 0xFFFF0000u);
    a[6] += w * __uint_as_float((unsigned)r.w << 16);
    a[7] += w * __uint_as_float((unsigned)r.w & 0xFFFF0000u);
}

// ---------------------------------------------------------------------------
// Fused MLP: h = relu(relu(x @ W1) @ W2).  PROVEN R4 form, byte-identical
// (163us, VGPR 64, WRITE 37.5MB).  DO NOT restructure: R1 reg-prefetch
// spilled (WRITE 190MB); R6 k-chunked GEMM2 spilled (VGPR 256, 360us).
// ---------------------------------------------------------------------------
__launch_bounds__(256)
__global__ void mlp_kernel(const float* __restrict__ x,
                           const float* __restrict__ W1,
                           const float* __restrict__ W2,
                           float* __restrict__ h0,
                           unsigned short* __restrict__ hb, int nN)
{
    __shared__ float smem[8704];
    float (*As)[68] = (float(*)[68])smem;            // 64 x 68
    float (*Bs)[68] = (float(*)[68])(smem + 4352);   // 64 x 68
    float (*Hs)[68] = (float(*)[68])smem;            // GEMM2 reuse
    float (*Ws)[68] = (float(*)[68])(smem + 4352);

    const int t  = threadIdx.x;
    const int ty = t >> 4;
    const int tx = t & 15;
    const int row0 = blockIdx.x * 64;

    const int srow = t >> 4;
    const int slk  = (t & 15) * 4;

    float acc[4][4] = {};

    for (int k0 = 0; k0 < 512; k0 += 64) {
        #pragma unroll
        for (int h = 0; h < 4; ++h) {
            int r = srow + 16 * h;
            int grow = row0 + r;
            float4 v = make_float4(0.f, 0.f, 0.f, 0.f);
            if (grow < nN) v = *(const float4*)&x[(size_t)grow * 512 + k0 + slk];
            *(float4*)&As[r][slk] = v;
        }
        #pragma unroll
        for (int h = 0; h < 4; ++h) {
            int r = srow + 16 * h;
            *(float4*)&Bs[r][slk] = *(const float4*)&W1[(size_t)(k0 + r) * 64 + slk];
        }
        __syncthreads();

        for (int kk = 0; kk < 64; kk += 4) {
            float4 b0 = *(float4*)&Bs[kk + 0][tx * 4];
            float4 b1 = *(float4*)&Bs[kk + 1][tx * 4];
            float4 b2 = *(float4*)&Bs[kk + 2][tx * 4];
            float4 b3 = *(float4*)&Bs[kk + 3][tx * 4];
            #pragma unroll
            for (int i = 0; i < 4; ++i) {
                float4 a = *(float4*)&As[ty * 4 + i][kk];
                acc[i][0] += a.x * b0.x + a.y * b1.x + a.z * b2.x + a.w * b3.x;
                acc[i][1] += a.x * b0.y + a.y * b1.y + a.z * b2.y + a.w * b3.y;
                acc[i][2] += a.x * b0.z + a.y * b1.z + a.z * b2.z + a.w * b3.z;
                acc[i][3] += a.x * b0.w + a.y * b1.w + a.z * b2.w + a.w * b3.w;
            }
        }
        __syncthreads();
    }

    #pragma unroll
    for (int i = 0; i < 4; ++i) {
        float4 o;
        o.x = acc[i][0] > 0.f ? acc[i][0] : 0.f;
        o.y = acc[i][1] > 0.f ? acc[i][1] : 0.f;
        o.z = acc[i][2] > 0.f ? acc[i][2] : 0.f;
        o.w = acc[i][3] > 0.f ? acc[i][3] : 0.f;
        *(float4*)&Hs[ty * 4 + i][tx * 4] = o;
    }
    #pragma unroll
    for (int qq = 0; qq < 4; ++qq) {
        int r = srow + 16 * qq;
        *(float4*)&Ws[r][slk] = *(const float4*)&W2[(size_t)r * 64 + slk];
    }
    __syncthreads();

    float acc2[4][4] = {};
    for (int kk = 0; kk < 64; kk += 4) {
        float4 b0 = *(float4*)&Ws[kk + 0][tx * 4];
        float4 b1 = *(float4*)&Ws[kk + 1][tx * 4];
        float4 b2 = *(float4*)&Ws[kk + 2][tx * 4];
        float4 b3 = *(float4*)&Ws[kk + 3][tx * 4];
        #pragma unroll
        for (int i = 0; i < 4; ++i) {
            float4 a = *(float4*)&Hs[ty * 4 + i][kk];
            acc2[i][0] += a.x * b0.x + a.y * b1.x + a.z * b2.x + a.w * b3.x;
            acc2[i][1] += a.x * b0.y + a.y * b1.y + a.z * b2.y + a.w * b3.y;
            acc2[i][2] += a.x * b0.z + a.y * b1.z + a.z * b2.z + a.w * b3.z;
            acc2[i][3] += a.x * b0.w + a.y * b1.w + a.z * b2.w + a.w * b3.w;
        }
    }

    #pragma unroll
    for (int i = 0; i < 4; ++i) {
        int grow = row0 + ty * 4 + i;
        if (grow < nN) {
            float4 o;
            o.x = acc2[i][0] > 0.f ? acc2[i][0] : 0.f;
            o.y = acc2[i][1] > 0.f ? acc2[i][1] : 0.f;
            o.z = acc2[i][2] > 0.f ? acc2[i][2] : 0.f;
            o.w = acc2[i][3] > 0.f ? acc2[i][3] : 0.f;
            *(float4*)&h0[(size_t)grow * 64 + tx * 4] = o;
            ushort4 ob = make_ushort4(f2b(o.x), f2b(o.y), f2b(o.z), f2b(o.w));
            *(ushort4*)&hb[(size_t)grow * 64 + tx * 4] = ob;
        }
    }
}

// ---------------------------------------------------------------------------
// CSR build (plain, by dst): count -> hierarchical scan -> atomic fill.
// After fill, rowptr[n] = END offset; start = rowptr[n-1] (0 for n=0).
// (R8's 4-segment CSR regressed 2x: avg seg-row degree 4 -> row overhead
//  dominated, + fp32 acc rmw traffic.  Full-table single pass wins.)
// ---------------------------------------------------------------------------
__launch_bounds__(256)
__global__ void count_kernel(const int* __restrict__ dst, int* __restrict__ rowptr, int nE)
{
    int e = blockIdx.x * 256 + threadIdx.x;
    if (e < nE) atomicAdd(&rowptr[dst[e]], 1);
}

__launch_bounds__(256)
__global__ void scanA(int* __restrict__ deg, int* __restrict__ bsum, int L)
{
    __shared__ int ts[256];
    const int t = threadIdx.x;
    const int base = blockIdx.x * 1024 + t * 4;
    int v0 = 0, v1 = 0, v2 = 0, v3 = 0;
    if (base + 3 < L) {
        int4 v = *(const int4*)&deg[base];
        v0 = v.x; v1 = v.y; v2 = v.z; v3 = v.w;
    } else {
        if (base + 0 < L) v0 = deg[base + 0];
        if (base + 1 < L) v1 = deg[base + 1];
        if (base + 2 < L) v2 = deg[base + 2];
        if (base + 3 < L) v3 = deg[base + 3];
    }
    int s = v0 + v1 + v2 + v3;
    ts[t] = s;
    __syncthreads();
    for (int d = 1; d < 256; d <<= 1) {
        int xv = (t >= d) ? ts[t - d] : 0;
        __syncthreads();
        ts[t] += xv;
        __syncthreads();
    }
    if (t == 255) bsum[blockIdx.x] = ts[255];
    int e0 = ts[t] - s;
    int e1 = e0 + v0;
    int e2 = e1 + v1;
    int e3 = e2 + v2;
    if (base + 3 < L) {
        *(int4*)&deg[base] = make_int4(e0, e1, e2, e3);
    } else {
        if (base + 0 < L) deg[base + 0] = e0;
        if (base + 1 < L) deg[base + 1] = e1;
        if (base + 2 < L) deg[base + 2] = e2;
        if (base + 3 < L) deg[base + 3] = e3;
    }
}

__launch_bounds__(256)
__global__ void scanB(int* __restrict__ bsum, int nB)
{
    __shared__ int ts[256];
    const int t = threadIdx.x;
    int v = (t < nB) ? bsum[t] : 0;
    ts[t] = v;
    __syncthreads();
    for (int d = 1; d < 256; d <<= 1) {
        int xv = (t >= d) ? ts[t - d] : 0;
        __syncthreads();
        ts[t] += xv;
        __syncthreads();
    }
    if (t < nB) bsum[t] = ts[t] - v;
}

__launch_bounds__(256)
__global__ void scanC(int* __restrict__ deg, const int* __restrict__ bsum, int L)
{
    const int i4 = (blockIdx.x * 256 + threadIdx.x) * 4;
    if (i4 >= L) return;
    const int b = bsum[i4 >> 10];
    if (i4 + 3 < L) {
        int4 v = *(int4*)&deg[i4];
        v.x += b; v.y += b; v.z += b; v.w += b;
        *(int4*)&deg[i4] = v;
    } else {
        for (int j = 0; j < 4 && i4 + j < L; ++j) deg[i4 + j] += b;
    }
}

__launch_bounds__(256)
__global__ void fill_kernel(const int* __restrict__ src, const int* __restrict__ dst,
                            const float* __restrict__ w,
                            int* __restrict__ rowptr,
                            int2* __restrict__ cwp, int nE)
{
    int e = blockIdx.x * 256 + threadIdx.x;
    if (e >= nE) return;
    int d = dst[e];
    int pos = atomicAdd(&rowptr[d], 1);
    cwp[pos] = make_int2(src[e], __float_as_int(w[e]));
}

// ---------------------------------------------------------------------------
// Fused pull-SpMM + gate, bf16 propagation, full-table single pass.
// R9: MLP (memory-level-parallelism) experiment.  Each wave processes TWO
// dst rows with interleaved predicated chains: per iteration 4 independent
// cwp loads + 4 independent 16B row-gathers in flight (R5 had 2; R4's
// 4-chain form measured 77 vs 80 us/hop -> partial MLP sensitivity).
// Lane map: g = lane>>3 (edge slot 0..7), q = lane&7 (16B channel octet).
// Direct predicated loads, no shfl in the loop; OOB slots w=0/col=0.
// ---------------------------------------------------------------------------
__launch_bounds__(256)
__global__ void spmm_fused(const int* __restrict__ rowptr,
                           const int2* __restrict__ cwp,
                           const unsigned short* __restrict__ cur,
                           unsigned short* __restrict__ nxt,
                           const int* __restrict__ idx,
                           const float* __restrict__ wp,
                           float* __restrict__ out,
                           int nN, int nI, int nodeBlocks)
{
    const int bid  = blockIdx.x;
    const int wid  = threadIdx.x >> 6;
    const int lane = threadIdx.x & 63;
    const int g = lane >> 3;   // edge slot 0..7
    const int q = lane & 7;    // channel octet (8 bf16 = 16B)

    if (bid < nodeBlocks) {
        // ---- node path: two rows per wave, interleaved chains ----
        const int n0 = (bid * 4 + wid) * 2;
        const int n1 = n0 + 1;
        if (n0 >= nN) return;
        const bool has1 = (n1 < nN);

        const int beg0 = (n0 == 0) ? 0 : rowptr[n0 - 1];
        const int end0 = rowptr[n0];
        const int beg1 = has1 ? rowptr[n0] : 0;
        const int end1 = has1 ? rowptr[n1] : 0;

        float a[8] = {}, b[8] = {}, c[8] = {}, d[8] = {};

        int e0 = beg0, e1 = beg1;
        while (e0 < end0 || e1 < end1) {
            int eA = e0 + g, eB = eA + 8;
            int eC = e1 + g, eD = eC + 8;
            int2 cA = (eA < end0) ? cwp[eA] : make_int2(0, 0);
            int2 cB = (eB < end0) ? cwp[eB] : make_int2(0, 0);
            int2 cC = (eC < end1) ? cwp[eC] : make_int2(0, 0);
            int2 cD = (eD < end1) ? cwp[eD] : make_int2(0, 0);
            int4 rA = *(const int4*)&cur[(size_t)cA.x * 64 + q * 8];
            int4 rB = *(const int4*)&cur[(size_t)cB.x * 64 + q * 8];
            int4 rC = *(const int4*)&cur[(size_t)cC.x * 64 + q * 8];
            int4 rD = *(const int4*)&cur[(size_t)cD.x * 64 + q * 8];
            fma8(a, __int_as_float(cA.y), rA);
            fma8(b, __int_as_float(cB.y), rB);
            fma8(c, __int_as_float(cC.y), rC);
            fma8(d, __int_as_float(cD.y), rD);
            e0 += 16; e1 += 16;
        }
        #pragma unroll
        for (int j = 0; j < 8; ++j) { a[j] += b[j]; c[j] += d[j]; }
        // reduce across the 8 edge slots (lane bits 3,4,5)
        #pragma unroll
        for (int j = 0; j < 8; ++j) {
            a[j] += __shfl_xor(a[j], 8);
            a[j] += __shfl_xor(a[j], 16);
            a[j] += __shfl_xor(a[j], 32);
            c[j] += __shfl_xor(c[j], 8);
            c[j] += __shfl_xor(c[j], 16);
            c[j] += __shfl_xor(c[j], 32);
        }
        if (g == 0) {
            int4 ob;
            ob.x = (int)(((unsigned)f2b(a[1]) << 16) | (unsigned)f2b(a[0]));
            ob.y = (int)(((unsigned)f2b(a[3]) << 16) | (unsigned)f2b(a[2]));
            ob.z = (int)(((unsigned)f2b(a[5]) << 16) | (unsigned)f2b(a[4]));
            ob.w = (int)(((unsigned)f2b(a[7]) << 16) | (unsigned)f2b(a[6]));
            *(int4*)&nxt[(size_t)n0 * 64 + q * 8] = ob;
            if (has1) {
                int4 oc;
                oc.x = (int)(((unsigned)f2b(c[1]) << 16) | (unsigned)f2b(c[0]));
                oc.y = (int)(((unsigned)f2b(c[3]) << 16) | (unsigned)f2b(c[2]));
                oc.z = (int)(((unsigned)f2b(c[5]) << 16) | (unsigned)f2b(c[4]));
                oc.w = (int)(((unsigned)f2b(c[7]) << 16) | (unsigned)f2b(c[6]));
                *(int4*)&nxt[(size_t)n1 * 64 + q * 8] = oc;
            }
        }
    } else {
        // ---- idx path: one output row per wave, 2 chains ----
        const int oi = (bid - nodeBlocks) * 4 + wid;
        if (oi >= nI) return;
        const int node = idx[oi];
        const int beg = (node == 0) ? 0 : rowptr[node - 1];
        const int end = rowptr[node];

        float a[8] = {}, b[8] = {};
        for (int e = beg; e < end; e += 16) {
            int eA = e + g, eB = eA + 8;
            int2 cA = (eA < end) ? cwp[eA] : make_int2(0, 0);
            int2 cB = (eB < end) ? cwp[eB] : make_int2(0, 0);
            int4 rA = *(const int4*)&cur[(size_t)cA.x * 64 + q * 8];
            int4 rB = *(const int4*)&cur[(size_t)cB.x * 64 + q * 8];
            fma8(a, __int_as_float(cA.y), rA);
            fma8(b, __int_as_float(cB.y), rB);
        }
        #pragma unroll
        for (int j = 0; j < 8; ++j) a[j] += b[j];
        #pragma unroll
        for (int j = 0; j < 8; ++j) {
            a[j] += __shfl_xor(a[j], 8);
            a[j] += __shfl_xor(a[j], 16);
            a[j] += __shfl_xor(a[j], 32);
        }
        // gate: s = row . wp (lane ch = q*8+j), reduce lane bits 0,1,2
        float s = 0.f;
        #pragma unroll
        for (int j = 0; j < 8; ++j) s += a[j] * wp[q * 8 + j];
        s += __shfl_xor(s, 1); s += __shfl_xor(s, 2); s += __shfl_xor(s, 4);
        float gate = 1.f / (1.f + __expf(-s));
        if (g == 0) {
            float* op = &out[(size_t)oi * 64 + q * 8];
            float4 p0 = *(float4*)op;
            float4 p1 = *(float4*)(op + 4);
            p0.x += gate * a[0]; p0.y += gate * a[1];
            p0.z += gate * a[2]; p0.w += gate * a[3];
            p1.x += gate * a[4]; p1.y += gate * a[5];
            p1.z += gate * a[6]; p1.w += gate * a[7];
            *(float4*)op = p0;
            *(float4*)(op + 4) = p1;
        }
    }
}

// ---------------------------------------------------------------------------
// Hop-0 gate: out[i] = sigmoid(h[idx[i]].wp) * h[idx[i]]  (fp32 h, inits out)
// ---------------------------------------------------------------------------
__launch_bounds__(256)
__global__ void gate_gather(const float* __restrict__ h,
                            const int* __restrict__ idx,
                            const float* __restrict__ wp,
                            float* __restrict__ out, int nI)
{
    int gid = blockIdx.x * 256 + threadIdx.x;
    int i = gid >> 6;
    if (i >= nI) return;
    int c = gid & 63;
    int n = idx[i];
    float v = h[(size_t)n * 64 + c];
    float s = v * wp[c];
    #pragma unroll
    for (int off = 32; off > 0; off >>= 1)
        s += __shfl_xor(s, off);
    float gate = 1.f / (1.f + __expf(-s));
    out[gid] = gate * v;
}

extern "C" void kernel_launch(void* const* d_in, const int* in_sizes, int n_in,
                              void* d_out, int out_size, void* d_ws, size_t ws_size,
                              hipStream_t stream) {
    const float* x    = (const float*)d_in[0];
    const int*   esrc = (const int*)d_in[1];
    const int*   edst = (const int*)d_in[2];
    const float* ew   = (const float*)d_in[3];
    const int*   nidx = (const int*)d_in[4];
    const float* W1   = (const float*)d_in[5];
    const float* W2   = (const float*)d_in[6];
    const float* wp   = (const float*)d_in[7];
    float* out = (float*)d_out;

    const int nN = in_sizes[0] / 512;
    const int nE = in_sizes[1];
    const int nI = in_sizes[4];

    // ws: h0 fp32 25.6M | bufA bf16 12.8M | bufB bf16 12.8M | rowptr 0.4M | cwp 12.8M
    float*          h0     = (float*)d_ws;
    unsigned short* bufA   = (unsigned short*)(h0 + (size_t)nN * C);
    unsigned short* bufB   = bufA + (size_t)nN * C;
    int*            rowptr = (int*)(bufB + (size_t)nN * C);
    int2*           cwp    = (int2*)(rowptr + nN);
    // scan block sums: bufB head is dead until the first hop writes nxt
    int*            bsum   = (int*)bufB;

    const int nB = (nN + 1023) / 1024;   // 98 for nN=100k (<=256)

    // --- CSR build (by dst) ---
    hipMemsetAsync(rowptr, 0, (size_t)nN * sizeof(int), stream);
    count_kernel<<<(nE + 255) / 256, 256, 0, stream>>>(edst, rowptr, nE);
    scanA<<<nB, 256, 0, stream>>>(rowptr, bsum, nN);
    scanB<<<1, 256, 0, stream>>>(bsum, nB);
    scanC<<<nB, 256, 0, stream>>>(rowptr, bsum, nN);
    fill_kernel<<<(nE + 255) / 256, 256, 0, stream>>>(esrc, edst, ew, rowptr, cwp, nE);

    // --- MLP (fp32 h0 + bf16 hb) ---
    mlp_kernel<<<(nN + 63) / 64, 256, 0, stream>>>(x, W1, W2, h0, bufA, nN);

    // hop 0 gate (initializes out)
    gate_gather<<<(nI * 64 + 255) / 256, 256, 0, stream>>>(h0, nidx, wp, out, nI);

    unsigned short* cur = bufA;
    unsigned short* nxt = bufB;
    const int nodeBlocks = (nN + 7) / 8;   // 2 rows/wave, 4 waves/block
    const int idxBlocks  = (nI + 3) / 4;
    for (int k = 0; k < 10; ++k) {
        // Final hop: nxt never read again -> idx-tail blocks only.
        const int nb = (k == 9) ? 0 : nodeBlocks;
        spmm_fused<<<nb + idxBlocks, 256, 0, stream>>>(
            rowptr, cwp, cur, nxt, nidx, wp, out, nN, nI, nb);
        unsigned short* tmp = cur; cur = nxt; nxt = tmp;
    }
}